// Round 1
// baseline (6355.868 us; speedup 1.0000x reference)
//
#include <hip/hip_runtime.h>

// MySimpleRNN: h_t = tanh(x_t @ W_xh + h_{t-1} @ W_hh + b_h), return all h_t.
// B=64, T=1024, D=256, U=512, fp32 in/out.
//
// Kernel A: xw = X@W_xh + b  (fp32 VALU tiled GEMM) -> staged in d_out.
// Kernel B: recurrence. 64 WGs = 4 groups (16 batches) x 16 col-slices (32 cols).
//   W_hh held in registers as bf16 hi/lo MFMA B-fragments (exact to ~2^-18).
//   h held as bf16 hi/lo, exchanged between the 16 WGs of a group through a
//   2-slot ring in d_ws with monotonic release/acquire flags (0xAA poison is
//   negative as int32 -> "flag >= t" spin needs no initialization).
//   3-term MFMA: h_hi@W_hi + h_hi@W_lo + h_lo@W_hi  (~fp32 accuracy).
//   h_t (fp32) overwrites its own xw slot in d_out in-place.

typedef __attribute__((ext_vector_type(8))) short short8;
typedef __attribute__((ext_vector_type(4))) float f32x4;

#define T_SZ 1024
#define U_SZ 512

__device__ __forceinline__ unsigned short f2bf(float f){
  unsigned u = __float_as_uint(f);
  u += 0x7FFFu + ((u >> 16) & 1u);           // round-to-nearest-even
  return (unsigned short)(u >> 16);
}
__device__ __forceinline__ float bf2f(unsigned short s){
  return __uint_as_float(((unsigned)s) << 16);
}

// ---------------- Kernel A: xw = X @ W_xh + b ----------------
// X: [65536,256] row-major, W: [256,512], out: [65536,512]
__global__ __launch_bounds__(256) void xw_gemm(const float* __restrict__ X,
                                               const float* __restrict__ W,
                                               const float* __restrict__ bias,
                                               float* __restrict__ out){
  __shared__ float As[16][132];   // [k][m], m-tile 128 (+4 pad)
  __shared__ float Bs[16][68];    // [k][n], n-tile 64  (+4 pad)
  const int tid = threadIdx.x;
  const int tx = tid & 15, ty = tid >> 4;
  const int row0 = blockIdx.x * 128;
  const int col0 = blockIdx.y * 64;
  float acc[8][4];
  #pragma unroll
  for(int a=0;a<8;a++)
    #pragma unroll
    for(int b=0;b<4;b++) acc[a][b]=0.f;

  for(int kc=0;kc<256;kc+=16){
    {
      const int m  = tid >> 2;
      const int kq = (tid & 3) * 4;
      #pragma unroll
      for(int h=0;h<2;h++){
        const float4 v = *(const float4*)&X[(size_t)(row0 + m + 64*h)*256 + kc + kq];
        As[kq+0][m+64*h]=v.x; As[kq+1][m+64*h]=v.y;
        As[kq+2][m+64*h]=v.z; As[kq+3][m+64*h]=v.w;
      }
    }
    {
      const int k = tid >> 4;
      const int c = (tid & 15) * 4;
      *(float4*)&Bs[k][c] = *(const float4*)&W[(size_t)(kc + k)*512 + col0 + c];
    }
    __syncthreads();
    #pragma unroll
    for(int k=0;k<16;k++){
      const float4 b4 = *(const float4*)&Bs[k][tx*4];
      const float4 a0 = *(const float4*)&As[k][ty*8];
      const float4 a1 = *(const float4*)&As[k][ty*8+4];
      const float av[8] = {a0.x,a0.y,a0.z,a0.w,a1.x,a1.y,a1.z,a1.w};
      const float bv[4] = {b4.x,b4.y,b4.z,b4.w};
      #pragma unroll
      for(int ii=0;ii<8;ii++)
        #pragma unroll
        for(int j=0;j<4;j++) acc[ii][j] = fmaf(av[ii], bv[j], acc[ii][j]);
    }
    __syncthreads();
  }
  #pragma unroll
  for(int ii=0;ii<8;ii++){
    const int row = row0 + ty*8 + ii;
    float4 o;
    o.x = acc[ii][0] + bias[col0+tx*4+0];
    o.y = acc[ii][1] + bias[col0+tx*4+1];
    o.z = acc[ii][2] + bias[col0+tx*4+2];
    o.w = acc[ii][3] + bias[col0+tx*4+3];
    *(float4*)&out[(size_t)row*512 + col0 + tx*4] = o;
  }
}

// ---------------- Kernel B: the recurrence ----------------
// grid 64, block 256 (4 waves). bid -> g = bid&3 (group / batch block of 16),
// i = bid>>2 (col slice of 32). wave w: nt = w&1 (16-col N-tile), kh = w>>1
// (K half, 256 each). W_hh B-frags resident in regs: 8 Ktiles x {hi,lo} = 64 VGPRs.
__global__ __launch_bounds__(256) void rnn_rec(const float* __restrict__ Whh,
                                               float* __restrict__ out,
                                               int* __restrict__ flags,
                                               unsigned short* __restrict__ ring){
  // A rows stride 520 shorts = 1040 B -> 16B-chunk column (m + quad) % 8: perfect
  __shared__ unsigned short Ahi[16][520];
  __shared__ unsigned short Alo[16][520];
  __shared__ float red[2][64][4];

  const int bid = blockIdx.x;
  const int g  = bid & 3;
  const int i  = bid >> 2;
  const int tid = threadIdx.x;
  const int lane = tid & 63;
  const int w  = tid >> 6;
  const int nt = w & 1;
  const int kh = w >> 1;
  const int ln = lane & 15;
  const int lq = lane >> 4;
  const int b0 = g * 16;
  const int c0 = i * 32;
  const int ncol0 = c0 + nt * 16;

  // --- load resident W_hh fragments (hi/lo bf16 split) ---
  short8 whi[8], wlo[8];
  #pragma unroll
  for(int kt=0;kt<8;kt++){
    short8 h8, l8;
    const int kb = kh*256 + kt*32 + lq*8;
    #pragma unroll
    for(int j=0;j<8;j++){
      const float wv = Whh[(size_t)(kb+j)*512 + ncol0 + ln];
      const unsigned short hb = f2bf(wv);
      const unsigned short lb = f2bf(wv - bf2f(hb));
      h8[j] = (short)hb; l8[j] = (short)lb;
    }
    whi[kt]=h8; wlo[kt]=l8;
  }
  // zero h_{-1}
  for(int idx=tid; idx<16*520; idx+=256){
    ((unsigned short*)Ahi)[idx]=0;
    ((unsigned short*)Alo)[idx]=0;
  }
  __syncthreads();

  const int myflag = g*16 + i;

  for(int t=0;t<T_SZ;t++){
    // prefetch xw_t (consumed in epilogue; issued early to hide latency)
    float xwv[4];
    if(kh==0){
      #pragma unroll
      for(int r=0;r<4;r++)
        xwv[r] = out[((size_t)(b0 + lq*4 + r)*T_SZ + t)*U_SZ + ncol0 + ln];
    }
    if(t>0){
      { // spin: each wave owns peers p with p%4==w (lanes 0..3, one each)
        const int s = lane;
        const int p = w + 4*s;
        bool done = (s>=4) || (p==i);
        while(__ballot(!done)){
          if(!done){
            const int f = __hip_atomic_load(&flags[g*16+p], __ATOMIC_RELAXED,
                                            __HIP_MEMORY_SCOPE_AGENT);
            done = (f >= t);
          }
        }
      }
      __builtin_amdgcn_fence(__ATOMIC_ACQUIRE, "agent");
      #pragma unroll
      for(int s2=0;s2<4;s2++){
        const int p = w + 4*s2;
        if(p==i) continue;                  // uniform per wave
        const size_t base = ((((size_t)((t-1)&1)*4 + g)*16 + p)*2)*512;
        const short8 vh = *(const short8*)(ring + base + (size_t)lane*8);
        const short8 vl = *(const short8*)(ring + base + 512 + (size_t)lane*8);
        const int kd = p*32 + lq*8;
        *(short8*)&Ahi[ln][kd] = vh;        // chunk layout == A-frag layout
        *(short8*)&Alo[ln][kd] = vl;
      }
    }
    __syncthreads();                        // B1: A (= h_{t-1}) complete

    f32x4 c_hh = {0.f,0.f,0.f,0.f}, c_hl = {0.f,0.f,0.f,0.f}, c_lh = {0.f,0.f,0.f,0.f};
    #pragma unroll
    for(int kt=0;kt<8;kt++){
      const int k = kh*256 + kt*32 + lq*8;
      const short8 ah = *(const short8*)&Ahi[ln][k];
      const short8 al = *(const short8*)&Alo[ln][k];
      c_hh = __builtin_amdgcn_mfma_f32_16x16x32_bf16(ah, whi[kt], c_hh, 0, 0, 0);
      c_hl = __builtin_amdgcn_mfma_f32_16x16x32_bf16(ah, wlo[kt], c_hl, 0, 0, 0);
      c_lh = __builtin_amdgcn_mfma_f32_16x16x32_bf16(al, whi[kt], c_lh, 0, 0, 0);
    }
    f32x4 csum = c_hh + c_hl + c_lh;
    if(kh==1) *(f32x4*)&red[nt][lane][0] = csum;
    __syncthreads();                        // B2: partials visible
    if(kh==0){
      const f32x4 o = *(const f32x4*)&red[nt][lane][0];
      csum += o;
      float hval[4];
      #pragma unroll
      for(int r=0;r<4;r++){
        float pre = csum[r] + xwv[r];
        pre = fminf(fmaxf(pre, -12.f), 12.f);
        const float e = __expf(2.f*pre);
        const float h = (e-1.f)/(e+1.f);    // tanh
        hval[r] = h;
        const unsigned short hb = f2bf(h);
        const unsigned short lb = f2bf(h - bf2f(hb));
        Ahi[lq*4+r][ncol0+ln] = hb;         // own cols of A for step t+1
        Alo[lq*4+r][ncol0+ln] = lb;
      }
      #pragma unroll
      for(int r=0;r<4;r++)                  // fp32 output, overwrites xw slot
        out[((size_t)(b0 + lq*4 + r)*T_SZ + t)*U_SZ + ncol0 + ln] = hval[r];
    }
    __syncthreads();                        // B3: own cols final in A
    if(w==3){                               // publisher wave (lightest duty)
      const int kb2 = c0 + lq*8;
      const short8 ph = *(const short8*)&Ahi[ln][kb2];
      const short8 pl = *(const short8*)&Alo[ln][kb2];
      const size_t base = ((((size_t)(t&1)*4 + g)*16 + i)*2)*512;
      *(short8*)(ring + base + (size_t)lane*8) = ph;
      *(short8*)(ring + base + 512 + (size_t)lane*8) = pl;
      if(lane==0)
        __hip_atomic_store(&flags[myflag], t+1, __ATOMIC_RELEASE,
                           __HIP_MEMORY_SCOPE_AGENT);
    }
    // waves 0..2 run ahead into t+1 (peer writes are disjoint from publish reads)
  }
}

extern "C" void kernel_launch(void* const* d_in, const int* in_sizes, int n_in,
                              void* d_out, int out_size, void* d_ws, size_t ws_size,
                              hipStream_t stream) {
  (void)in_sizes; (void)n_in; (void)out_size; (void)ws_size;
  const float* X   = (const float*)d_in[0];  // [64,1024,256]
  const float* Wxh = (const float*)d_in[1];  // [256,512]
  const float* Whh = (const float*)d_in[2];  // [512,512]
  const float* bh  = (const float*)d_in[3];  // [512]
  float* out = (float*)d_out;                // [64,1024,512]

  int* flags = (int*)d_ws;                                   // 64 ints (poison<0 OK)
  unsigned short* ring = (unsigned short*)((char*)d_ws + 1024); // 256 KB ring

  xw_gemm<<<dim3(512, 8), 256, 0, stream>>>(X, Wxh, bh, out);
  rnn_rec<<<64, 256, 0, stream>>>(Whh, out, flags, ring);
}

// Round 2
// 3688.319 us; speedup vs baseline: 1.7232x; 1.7232x over previous
//
#include <hip/hip_runtime.h>

// MySimpleRNN: h_t = tanh(x_t @ W_xh + h_{t-1} @ W_hh + b_h), return all h_t.
// B=64, T=1024, D=256, U=512, fp32 in/out.
//
// Kernel A: xw = X@W_xh + b  (fp32 VALU tiled GEMM) -> staged in d_out.
// Kernel B: recurrence. 64 WGs = 4 groups (16 batches) x 16 col-slices (32 cols).
//   Round-2 restructure: ring/flags are RELAXED agent-scope atomics (bypass L2,
//   no buffer_wbl2 / buffer_inv fences); producer waves publish their own halves
//   right after tanh (2 flags/WG, no third barrier); h fp32 HBM store delayed one
//   step and xw prefetched one step ahead so no HBM-latency op drains on the
//   critical path. 2 barriers/step.

typedef __attribute__((ext_vector_type(8))) short short8;
typedef __attribute__((ext_vector_type(4))) float f32x4;

#define T_SZ 1024
#define U_SZ 512

typedef union { unsigned long long q[2]; short8 v; } chunk16;

__device__ __forceinline__ unsigned short f2bf(float f){
  unsigned u = __float_as_uint(f);
  u += 0x7FFFu + ((u >> 16) & 1u);           // round-to-nearest-even
  return (unsigned short)(u >> 16);
}
__device__ __forceinline__ float bf2f(unsigned short s){
  return __uint_as_float(((unsigned)s) << 16);
}

// ---------------- Kernel A: xw = X @ W_xh + b ----------------
// X: [65536,256] row-major, W: [256,512], out: [65536,512]
__global__ __launch_bounds__(256) void xw_gemm(const float* __restrict__ X,
                                               const float* __restrict__ W,
                                               const float* __restrict__ bias,
                                               float* __restrict__ out){
  __shared__ float As[16][132];   // [k][m], m-tile 128 (+4 pad)
  __shared__ float Bs[16][68];    // [k][n], n-tile 64  (+4 pad)
  const int tid = threadIdx.x;
  const int tx = tid & 15, ty = tid >> 4;
  const int row0 = blockIdx.x * 128;
  const int col0 = blockIdx.y * 64;
  float acc[8][4];
  #pragma unroll
  for(int a=0;a<8;a++)
    #pragma unroll
    for(int b=0;b<4;b++) acc[a][b]=0.f;

  for(int kc=0;kc<256;kc+=16){
    {
      const int m  = tid >> 2;
      const int kq = (tid & 3) * 4;
      #pragma unroll
      for(int h=0;h<2;h++){
        const float4 v = *(const float4*)&X[(size_t)(row0 + m + 64*h)*256 + kc + kq];
        As[kq+0][m+64*h]=v.x; As[kq+1][m+64*h]=v.y;
        As[kq+2][m+64*h]=v.z; As[kq+3][m+64*h]=v.w;
      }
    }
    {
      const int k = tid >> 4;
      const int c = (tid & 15) * 4;
      *(float4*)&Bs[k][c] = *(const float4*)&W[(size_t)(kc + k)*512 + col0 + c];
    }
    __syncthreads();
    #pragma unroll
    for(int k=0;k<16;k++){
      const float4 b4 = *(const float4*)&Bs[k][tx*4];
      const float4 a0 = *(const float4*)&As[k][ty*8];
      const float4 a1 = *(const float4*)&As[k][ty*8+4];
      const float av[8] = {a0.x,a0.y,a0.z,a0.w,a1.x,a1.y,a1.z,a1.w};
      const float bv[4] = {b4.x,b4.y,b4.z,b4.w};
      #pragma unroll
      for(int ii=0;ii<8;ii++)
        #pragma unroll
        for(int j=0;j<4;j++) acc[ii][j] = fmaf(av[ii], bv[j], acc[ii][j]);
    }
    __syncthreads();
  }
  #pragma unroll
  for(int ii=0;ii<8;ii++){
    const int row = row0 + ty*8 + ii;
    float4 o;
    o.x = acc[ii][0] + bias[col0+tx*4+0];
    o.y = acc[ii][1] + bias[col0+tx*4+1];
    o.z = acc[ii][2] + bias[col0+tx*4+2];
    o.w = acc[ii][3] + bias[col0+tx*4+3];
    *(float4*)&out[(size_t)row*512 + col0 + tx*4] = o;
  }
}

// ---------------- Kernel B: the recurrence ----------------
// grid 64, block 256 (4 waves). bid -> g = bid&3 (group / 16-batch block),
// i = bid>>2 (col slice of 32). wave w: nt = w&1 (16-col N-tile), kh = w>>1
// (K half, 256 each). W_hh B-frags resident in regs: 8 Ktiles x {hi,lo} = 64 VGPRs.
__global__ __launch_bounds__(256, 1) void rnn_rec(const float* __restrict__ Whh,
                                                  float* __restrict__ out,
                                                  int* __restrict__ flags,
                                                  unsigned short* __restrict__ ring){
  __shared__ unsigned short Ahi[16][520];
  __shared__ unsigned short Alo[16][520];
  __shared__ float red[2][64][4];

  const int bid = blockIdx.x;
  const int g  = bid & 3;
  const int i  = bid >> 2;
  const int tid = threadIdx.x;
  const int lane = tid & 63;
  const int w  = tid >> 6;
  const int nt = w & 1;
  const int kh = w >> 1;
  const int ln = lane & 15;
  const int lq = lane >> 4;
  const int b0 = g * 16;
  const int c0 = i * 32;
  const int ncol0 = c0 + nt * 16;

  // --- load resident W_hh fragments (hi/lo bf16 split) ---
  short8 whi[8], wlo[8];
  #pragma unroll
  for(int kt=0;kt<8;kt++){
    short8 h8, l8;
    const int kb = kh*256 + kt*32 + lq*8;
    #pragma unroll
    for(int j=0;j<8;j++){
      const float wv = Whh[(size_t)(kb+j)*512 + ncol0 + ln];
      const unsigned short hb = f2bf(wv);
      const unsigned short lb = f2bf(wv - bf2f(hb));
      h8[j] = (short)hb; l8[j] = (short)lb;
    }
    whi[kt]=h8; wlo[kt]=l8;
  }
  // zero h_{-1}
  for(int idx=tid; idx<16*520; idx+=256){
    ((unsigned short*)Ahi)[idx]=0;
    ((unsigned short*)Alo)[idx]=0;
  }
  __syncthreads();

  float xwv[4] = {0.f,0.f,0.f,0.f};
  float hprev[4] = {0.f,0.f,0.f,0.f};
  if(kh==0){
    #pragma unroll
    for(int r=0;r<4;r++)
      xwv[r] = out[((size_t)(b0 + lq*4 + r)*T_SZ + 0)*U_SZ + ncol0 + ln];
  }

  for(int t=0;t<T_SZ;t++){
    if(t>0){
      // delayed fp32 h-store for t-1 (issued early, drains a full step later)
      if(kh==0){
        #pragma unroll
        for(int r=0;r<4;r++)
          out[((size_t)(b0 + lq*4 + r)*T_SZ + (t-1))*U_SZ + ncol0 + ln] = hprev[r];
      }
      { // spin: lanes 0..7 each own one (peer, half) flag
        const int s2 = lane >> 1;
        const int ntf = lane & 1;
        const int p = w + 4*s2;
        bool done = (lane>=8) || (p==i);
        while(__ballot(!done)){
          if(!done){
            const int f = __hip_atomic_load(&flags[((g*16+p)<<1)|ntf],
                                            __ATOMIC_RELAXED, __HIP_MEMORY_SCOPE_AGENT);
            done = (f >= t);
          }
        }
      }
      asm volatile("" ::: "memory");       // compiler ordering: poll -> ring reads
      const size_t slot = (size_t)((t-1)&1);
      #pragma unroll
      for(int s3=0;s3<4;s3++){
        const int p = w + 4*s3;
        if(p==i) continue;                  // uniform per wave
        const unsigned long long* rb =
            (const unsigned long long*)ring + ((slot*4 + g)*16 + p)*256;
        chunk16 ch, cl;
        ch.q[0] = __hip_atomic_load(rb + (size_t)lane*2 + 0,   __ATOMIC_RELAXED, __HIP_MEMORY_SCOPE_AGENT);
        ch.q[1] = __hip_atomic_load(rb + (size_t)lane*2 + 1,   __ATOMIC_RELAXED, __HIP_MEMORY_SCOPE_AGENT);
        cl.q[0] = __hip_atomic_load(rb + 128 + (size_t)lane*2, __ATOMIC_RELAXED, __HIP_MEMORY_SCOPE_AGENT);
        cl.q[1] = __hip_atomic_load(rb + 129 + (size_t)lane*2, __ATOMIC_RELAXED, __HIP_MEMORY_SCOPE_AGENT);
        const int kd = p*32 + lq*8;
        *(short8*)&Ahi[ln][kd] = ch.v;      // chunk layout == A-frag layout
        *(short8*)&Alo[ln][kd] = cl.v;
      }
    }
    __syncthreads();                        // B1: A (= h_{t-1}) complete

    f32x4 c_hh = {0.f,0.f,0.f,0.f}, c_hl = {0.f,0.f,0.f,0.f}, c_lh = {0.f,0.f,0.f,0.f};
    #pragma unroll
    for(int kt=0;kt<8;kt++){
      const int k = kh*256 + kt*32 + lq*8;
      const short8 ah = *(const short8*)&Ahi[ln][k];
      const short8 al = *(const short8*)&Alo[ln][k];
      c_hh = __builtin_amdgcn_mfma_f32_16x16x32_bf16(ah, whi[kt], c_hh, 0, 0, 0);
      c_hl = __builtin_amdgcn_mfma_f32_16x16x32_bf16(ah, wlo[kt], c_hl, 0, 0, 0);
      c_lh = __builtin_amdgcn_mfma_f32_16x16x32_bf16(al, whi[kt], c_lh, 0, 0, 0);
    }
    f32x4 csum = c_hh + c_hl + c_lh;
    if(kh==1) *(f32x4*)&red[nt][lane][0] = csum;
    __syncthreads();                        // B2: partials visible
    if(kh==0){
      const f32x4 o = *(const f32x4*)&red[nt][lane][0];
      csum += o;
      #pragma unroll
      for(int r=0;r<4;r++){
        float pre = csum[r] + xwv[r];
        pre = fminf(fmaxf(pre, -12.f), 12.f);
        const float e = __expf(2.f*pre);
        const float h = (e-1.f)/(e+1.f);    // tanh
        hprev[r] = h;
        const unsigned short hb = f2bf(h);
        const unsigned short lb = f2bf(h - bf2f(hb));
        Ahi[lq*4+r][ncol0+ln] = hb;         // own cols of A for step t+1
        Alo[lq*4+r][ncol0+ln] = lb;
      }
      // publish own 16-col half: LDS readback (A-chunk layout) -> ring atomics
      {
        const int c  = lane & 31;
        const int m  = c >> 1;
        const int q  = nt*2 + (c & 1);
        const int sel = lane >> 5;          // 0: hi plane, 1: lo plane
        const unsigned short* src = sel ? &Alo[m][c0 + q*8] : &Ahi[m][c0 + q*8];
        chunk16 ck; ck.v = *(const short8*)src;
        unsigned long long* rb = (unsigned long long*)ring
            + (((size_t)(t&1)*4 + g)*16 + i)*256 + (size_t)sel*128 + (size_t)(q*16 + m)*2;
        __hip_atomic_store(rb+0, ck.q[0], __ATOMIC_RELAXED, __HIP_MEMORY_SCOPE_AGENT);
        __hip_atomic_store(rb+1, ck.q[1], __ATOMIC_RELAXED, __HIP_MEMORY_SCOPE_AGENT);
      }
      asm volatile("s_waitcnt vmcnt(0)" ::: "memory");   // ring visible before flag
      if(lane==0)
        __hip_atomic_store(&flags[((g*16+i)<<1)|nt], t+1,
                           __ATOMIC_RELAXED, __HIP_MEMORY_SCOPE_AGENT);
      // prefetch xw for t+1 (after flag: never drained on critical path)
      {
        const int tn = (t < T_SZ-1) ? t+1 : t;
        #pragma unroll
        for(int r=0;r<4;r++)
          xwv[r] = out[((size_t)(b0 + lq*4 + r)*T_SZ + tn)*U_SZ + ncol0 + ln];
      }
    }
    // no third barrier: peer-chunk LDS writes (next spin) are disjoint from
    // own-col epilogue writes; B1(t+1) orders everything before the next MFMA.
  }
  if(kh==0){
    #pragma unroll
    for(int r=0;r<4;r++)
      out[((size_t)(b0 + lq*4 + r)*T_SZ + (T_SZ-1))*U_SZ + ncol0 + ln] = hprev[r];
  }
}

extern "C" void kernel_launch(void* const* d_in, const int* in_sizes, int n_in,
                              void* d_out, int out_size, void* d_ws, size_t ws_size,
                              hipStream_t stream) {
  (void)in_sizes; (void)n_in; (void)out_size; (void)ws_size;
  const float* X   = (const float*)d_in[0];  // [64,1024,256]
  const float* Wxh = (const float*)d_in[1];  // [256,512]
  const float* Whh = (const float*)d_in[2];  // [512,512]
  const float* bh  = (const float*)d_in[3];  // [512]
  float* out = (float*)d_out;                // [64,1024,512]

  int* flags = (int*)d_ws;                                      // 128 ints (poison<0 OK)
  unsigned short* ring = (unsigned short*)((char*)d_ws + 1024); // 256 KB ring

  xw_gemm<<<dim3(512, 8), 256, 0, stream>>>(X, Wxh, bh, out);
  rnn_rec<<<64, 256, 0, stream>>>(Whh, out, flags, ring);
}